// Round 2
// baseline (169.610 us; speedup 1.0000x reference)
//
#include <hip/hip_runtime.h>
#include <hip/hip_bf16.h>

typedef short s16x8 __attribute__((ext_vector_type(8)));
typedef float f32x4 __attribute__((ext_vector_type(4)));

constexpr int Bb = 2, NQ = 13294, Hh = 8, HD = 32;
constexpr int Mrows = Bb * NQ; // 26588

__device__ inline short bf16_of(float f) {
  __hip_bfloat16 h = __float2bfloat16(f);
  return *reinterpret_cast<short*>(&h);
}

// C = A[M,256] @ W[256,N] + bias. A: fp32 or bf16 (ABF16). W,bias fp32.
// f32 accum via bf16 MFMA. 64x64 tile, 4 waves.
// MODE 0: bf16 scatter to vproj[B][H][NQ][HD]; 1: bf16 offaw cols 0..255 (stride 384);
// MODE 2: bf16 offaw cols 256..383 (stride 384); 3: fp32 linear stride 256 (d_out).
template<int N, int MODE, bool ABF16>
__global__ __launch_bounds__(256) void gemm_k(
    const void* __restrict__ Araw, const float* __restrict__ W,
    const float* __restrict__ bias, void* __restrict__ outraw)
{
  __shared__ short As[64][40];   // +8 pad: breaks bank conflict on ds_read_b128
  __shared__ short Bs[64][40];   // Bs[n][k] (B staged transposed)
  const int row0 = blockIdx.x * 64, col0 = blockIdx.y * 64;
  const int tid = threadIdx.x;
  const int lane = tid & 63, wave = tid >> 6;
  f32x4 acc[4] = {};

  const int ar = tid >> 2, ak = (tid & 3) * 8;       // A stage: 64 rows x 32 k
  int grow = row0 + ar; if (grow >= Mrows) grow = Mrows - 1;
  const int kk = tid & 31, nb = (tid >> 5) * 8;      // B stage: transpose on write

  for (int kt = 0; kt < 256; kt += 32) {
    s16x8 av;
    if constexpr (ABF16) {
      av = *(const s16x8*)((const short*)Araw + grow * 256 + kt + ak);
    } else {
      const float* A = (const float*)Araw;
      f32x4 a0 = *(const f32x4*)(A + grow * 256 + kt + ak);
      f32x4 a1 = *(const f32x4*)(A + grow * 256 + kt + ak + 4);
#pragma unroll
      for (int i = 0; i < 4; i++) { av[i] = bf16_of(a0[i]); av[4 + i] = bf16_of(a1[i]); }
    }
    *(s16x8*)(&As[ar][ak]) = av;

    f32x4 w0 = *(const f32x4*)(W + (kt + kk) * N + col0 + nb);
    f32x4 w1 = *(const f32x4*)(W + (kt + kk) * N + col0 + nb + 4);
#pragma unroll
    for (int i = 0; i < 4; i++) { Bs[nb + i][kk] = bf16_of(w0[i]); Bs[nb + 4 + i][kk] = bf16_of(w1[i]); }
    __syncthreads();

    // wave owns 16-col strip; lane&15 = col/row-in-frag, (lane>>4)*8 = k offset
    s16x8 bfr = *(const s16x8*)(&Bs[wave * 16 + (lane & 15)][(lane >> 4) * 8]);
#pragma unroll
    for (int m = 0; m < 4; m++) {
      s16x8 afr = *(const s16x8*)(&As[m * 16 + (lane & 15)][(lane >> 4) * 8]);
      acc[m] = __builtin_amdgcn_mfma_f32_16x16x32_bf16(afr, bfr, acc[m], 0, 0, 0);
    }
    __syncthreads();
  }

  // D mapping (m89-verified): col = lane&15, row = (lane>>4)*4 + reg
  const int colL = col0 + wave * 16 + (lane & 15);
  const float bvf = bias[colL];
#pragma unroll
  for (int m = 0; m < 4; m++) {
#pragma unroll
    for (int r = 0; r < 4; r++) {
      int rowL = row0 + m * 16 + (lane >> 4) * 4 + r;
      if (rowL < Mrows) {
        float v = acc[m][r] + bvf;
        if constexpr (MODE == 0) {
          int b = rowL / NQ, n = rowL - (rowL / NQ) * NQ;
          int h = colL >> 5, c = colL & 31;
          ((__hip_bfloat16*)outraw)[((b * Hh + h) * NQ + n) * HD + c] = __float2bfloat16(v);
        } else if constexpr (MODE == 1) {
          ((__hip_bfloat16*)outraw)[rowL * 384 + colL] = __float2bfloat16(v);
        } else if constexpr (MODE == 2) {
          ((__hip_bfloat16*)outraw)[rowL * 384 + 256 + colL] = __float2bfloat16(v);
        } else {
          ((float*)outraw)[rowL * 256 + colL] = v;
        }
      }
    }
  }
}

// One block per (b,q). 8 heads x 32 channels = 256 threads.
// Phase A: 16 lanes/head build sample descriptors (softmax fused).
// Phase B: 32 channel-lanes/head gather 16 samples x 4 corners (coalesced 64B).
__global__ __launch_bounds__(256) void sample_k(
    const __hip_bfloat16* __restrict__ vproj,
    const __hip_bfloat16* __restrict__ offaw,
    const float* __restrict__ refp,
    __hip_bfloat16* __restrict__ interm)
{
  __shared__ float dw[8][16][4];
  __shared__ int   didx[8][16][4];
  const int bq = blockIdx.x;
  const int b = bq / NQ;
  const int tid = threadIdx.x;
  const int h = tid >> 5, sub = tid & 31;

  if (sub < 16) {
    const int l = sub >> 2, p = sub & 3;
    const int dims[4]   = {100, 50, 25, 13};
    const int starts[4] = {0, 10000, 12500, 13125};
    const int lw = dims[l], lh = dims[l];
    const int base384 = bq * 384;
    float offx  = __bfloat162float(offaw[base384 + h * 32 + l * 8 + p * 2 + 0]);
    float offy  = __bfloat162float(offaw[base384 + h * 32 + l * 8 + p * 2 + 1]);
    float logit = __bfloat162float(offaw[base384 + 256 + h * 16 + l * 4 + p]);
    float rx = refp[(bq * 4 + l) * 2 + 0];
    float ry = refp[(bq * 4 + l) * 2 + 1];
    // align_corners=False: gx = loc_x*lw - 0.5 = rx*lw + offx - 0.5
    float gx = rx * (float)lw + offx - 0.5f;
    float gy = ry * (float)lh + offy - 0.5f;
    // softmax over the 16 (l,p) lanes of this head
    float mx = logit;
#pragma unroll
    for (int d = 1; d < 16; d <<= 1) mx = fmaxf(mx, __shfl_xor(mx, d));
    float e = __expf(logit - mx);
    float s = e;
#pragma unroll
    for (int d = 1; d < 16; d <<= 1) s += __shfl_xor(s, d);
    float aw = e / s;
    float x0f = floorf(gx), y0f = floorf(gy);
    int x0 = (int)x0f, y0 = (int)y0f;
    float wx = gx - x0f, wy = gy - y0f;
    const int pbase = (b * Hh + h) * NQ + starts[l];
#pragma unroll
    for (int k = 0; k < 4; k++) {
      int xi = x0 + (k & 1), yi = y0 + (k >> 1);
      bool valid = (xi >= 0) && (xi < lw) && (yi >= 0) && (yi < lh);
      int xc = min(max(xi, 0), lw - 1), yc = min(max(yi, 0), lh - 1);
      float wcv = ((k & 1) ? wx : 1.f - wx) * ((k >> 1) ? wy : 1.f - wy);
      dw[h][sub][k]   = valid ? wcv * aw : 0.f;
      didx[h][sub][k] = pbase + yc * lw + xc;
    }
  }
  __syncthreads();

  const int c = sub;
  float acc = 0.f;
#pragma unroll 4
  for (int lp = 0; lp < 16; lp++) {
    float4 wv = *(const float4*)(&dw[h][lp][0]);    // LDS broadcast (free)
    int4   iv = *(const int4*)(&didx[h][lp][0]);
    acc += wv.x * __bfloat162float(vproj[iv.x * HD + c]);
    acc += wv.y * __bfloat162float(vproj[iv.y * HD + c]);
    acc += wv.z * __bfloat162float(vproj[iv.z * HD + c]);
    acc += wv.w * __bfloat162float(vproj[iv.w * HD + c]);
  }
  interm[bq * 256 + h * 32 + c] = __float2bfloat16(acc);
}

extern "C" void kernel_launch(void* const* d_in, const int* in_sizes, int n_in,
                              void* d_out, int out_size, void* d_ws, size_t ws_size,
                              hipStream_t stream)
{
  const float* query = (const float*)d_in[0];
  const float* refp  = (const float*)d_in[1];
  const float* value = (const float*)d_in[2];
  // d_in[3] = spatial_shapes (static, hardcoded)
  const float* Wso = (const float*)d_in[4];
  const float* bso = (const float*)d_in[5];
  const float* Waw = (const float*)d_in[6];
  const float* baw = (const float*)d_in[7];
  const float* Wv  = (const float*)d_in[8];
  const float* bv  = (const float*)d_in[9];
  const float* Wo  = (const float*)d_in[10];
  const float* bo  = (const float*)d_in[11];

  char* ws = (char*)d_ws;
  __hip_bfloat16* vproj  = (__hip_bfloat16*)ws;                 // 2*8*13294*32 bf16 = 13,613,056 B
  __hip_bfloat16* offaw  = (__hip_bfloat16*)(ws + 13613056);    // 26588*384 bf16  = 20,419,584 B
  __hip_bfloat16* interm = (__hip_bfloat16*)(ws + 34032640);    // 26588*256 bf16  = 13,613,056 B
  float* out = (float*)d_out;

  dim3 blk(256);
  gemm_k<256, 0, false><<<dim3(416, 4), blk, 0, stream>>>(value, Wv, bv, vproj);
  gemm_k<256, 1, false><<<dim3(416, 4), blk, 0, stream>>>(query, Wso, bso, offaw);
  gemm_k<128, 2, false><<<dim3(416, 2), blk, 0, stream>>>(query, Waw, baw, offaw);
  sample_k<<<dim3(Bb * NQ), blk, 0, stream>>>(vproj, offaw, refp, interm);
  gemm_k<256, 3, true><<<dim3(416, 4), blk, 0, stream>>>(interm, Wo, bo, out);
}